// Round 8
// baseline (40.769 us; speedup 1.0000x reference)
//
#include <hip/hip_runtime.h>

// R8: R7 pipeline + 8-wave N-split for 4 waves/SIMD.
//   Wave (wv_m, wv_n): rows wv_m*16..+15, N-frags wv_n*4..(4|3).
//   BK=32, 3 LDS buffers; exactly 2 gload_lds per wave per stage
//   (x: 8 rows/wave, B: 16 rows/wave). Stage: issue(t+2) -> compute(t)
//   -> s_waitcnt vmcnt(2) -> s_barrier. Never vmcnt(0) in main loop.
//   XOR swizzle both sides (pre-swizzled global source + swizzled ds_read).

typedef __attribute__((ext_vector_type(8))) short bf16x8;
typedef __attribute__((ext_vector_type(4))) float f32x4;

#define KP1 832     // Weff K padded (784 -> 26*32)
#define NP  112     // hidden N padded (100 -> 7*16)
#define NPB 128     // B-staging rows (uniform issue count)
#define K2P 128     // GEMM2/3 K padded
#define BM  64
#define NT  512

#define W2T_OFF (NPB * KP1)             // 106496
#define W3T_OFF (W2T_OFF + NP * K2P)    // 120832
#define WS_USHORTS (W3T_OFF + 16 * K2P) // 122880 (245,760 B)

#define WAITV2 asm volatile("s_waitcnt vmcnt(2)" ::: "memory")
#define WAITV0 asm volatile("s_waitcnt vmcnt(0)" ::: "memory")
#define BAR    __builtin_amdgcn_s_barrier()

__device__ __forceinline__ unsigned short f2bf(float f) {
    unsigned int u = __float_as_uint(f);
    u += 0x7FFFu + ((u >> 16) & 1u);    // RNE
    return (unsigned short)(u >> 16);
}

__device__ __forceinline__ unsigned int pkbf(float a, float b) {
    unsigned int r;
    asm("v_cvt_pk_bf16_f32 %0, %1, %2" : "=v"(r) : "v"(a), "v"(b));
    return r;
}

__device__ __forceinline__ bf16x8 cvt8(float4 a, float4 b) {
    union { unsigned int w[4]; bf16x8 v; } u;
    u.w[0] = pkbf(a.x, a.y);
    u.w[1] = pkbf(a.z, a.w);
    u.w[2] = pkbf(b.x, b.y);
    u.w[3] = pkbf(b.z, b.w);
    return u.v;
}

__device__ __forceinline__ void gload_lds16(const void* g, void* l) {
    __builtin_amdgcn_global_load_lds(
        (const __attribute__((address_space(1))) unsigned int*)g,
        (__attribute__((address_space(3))) unsigned int*)l, 16, 0, 0);
}

// ---------------- Kernel A: weights -> bf16, transposed, padded
__global__ void build_weights(const float* __restrict__ w_conv,
                              const float* __restrict__ W1,
                              const float* __restrict__ W2,
                              const float* __restrict__ W3,
                              unsigned short* __restrict__ ws) {
    const int idx = blockIdx.x * 256 + threadIdx.x;
    if (idx >= WS_USHORTS) return;
    float v = 0.f;
    if (idx < W2T_OFF) {                       // weff_t[col][p], 128 rows
        const int col = idx / KP1, p = idx % KP1;
        if (col < 100 && p < 784) {
            const int y = p / 28, xx = p % 28;
#pragma unroll
            for (int ky = 0; ky < 3; ++ky) {
                const int py = y - ky;
                if (py < 0 || py >= 26) continue;
#pragma unroll
                for (int kx = 0; kx < 3; ++kx) {
                    const int px = xx - kx;
                    if (px < 0 || px >= 26) continue;
                    v += w_conv[ky * 3 + kx] * W1[(py * 26 + px) * 100 + col];
                }
            }
        }
    } else if (idx < W3T_OFF) {                // w2t[col][k]
        const int r = idx - W2T_OFF;
        const int col = r / K2P, k = r % K2P;
        if (col < 100 && k < 100) v = W2[k * 100 + col];
    } else {                                   // w3t[col][k]
        const int r = idx - W3T_OFF;
        const int col = r / K2P, k = r % K2P;
        if (col < 10 && k < 100) v = W3[k * 10 + col];
    }
    ws[idx] = f2bf(v);
}

// ---------------- Kernel B: fused
__global__ __launch_bounds__(NT, 4)
void fused(const float* __restrict__ x,
           const unsigned short* __restrict__ wst,
           const float* __restrict__ b1,
           const float* __restrict__ b2,
           const float* __restrict__ b3,
           float* __restrict__ out) {
    __shared__ __attribute__((aligned(16))) float          xs[3][64][32];   // 24576 B
    __shared__ __attribute__((aligned(16))) unsigned short bs[3][128][32];  // 24576 B
    __shared__ __attribute__((aligned(16))) unsigned short h1[64][136];     // 17408 B
    unsigned short (*h2)[136] = reinterpret_cast<unsigned short(*)[136]>(&xs[0][0][0]);

    const int tid  = threadIdx.x;
    const int lane = tid & 63;
    const int wv   = tid >> 6;       // 0..7
    const int wv_m = wv >> 1;        // 0..3 : rows wv_m*16..+15
    const int wv_n = wv & 1;         // 0..1 : frags wv_n*4 .. (+3 | +2)
    const int nb   = wv_n * 4;
    const int l15  = lane & 15;
    const int lk   = lane >> 4;      // 0..3
    const int b0   = blockIdx.x * BM;
    const int wr   = wv_m * 16;

    const unsigned short* weff = wst;
    const unsigned short* w2t  = wst + W2T_OFF;
    const unsigned short* w3t  = wst + W3T_OFF;

    f32x4 acc[4];
#pragma unroll
    for (int j = 0; j < 4; ++j) acc[j] = (f32x4){0.f, 0.f, 0.f, 0.f};

    // staging addresses (source-side pre-swizzle; LDS dest linear)
    const int xrow = wv * 8 + (lane >> 3);               // 8 rows/wave
    const char* xsrc = (const char*)(x + (size_t)(b0 + xrow) * 784)
                     + (((lane & 7) ^ (xrow & 7)) << 4);
    const int brow = wv * 16 + (lane >> 2);              // 16 rows/wave
    const char* bsrc = (const char*)(weff + (size_t)brow * KP1)
                     + (((lane & 3) ^ (brow & 3)) << 4);

    auto issue = [&](int kt, float* xb, unsigned short* bb) {
        gload_lds16(xsrc + (size_t)kt * 128, (void*)(xb + wv * 8 * 32));
        gload_lds16(bsrc + (size_t)kt * 64,  (void*)(bb + wv * 16 * 32));
    };

    auto computeStage = [&](const float* xb, const unsigned short* bb) {
        const int r = wr + l15;
        const char* ap = (const char*)(xb + (size_t)r * 32);
        const int sA = (r & 7) << 4;
        const float4 lo = *reinterpret_cast<const float4*>(ap + ((lk * 32) ^ sA));
        const float4 hi = *reinterpret_cast<const float4*>(ap + ((lk * 32 + 16) ^ sA));
        const bf16x8 af = cvt8(lo, hi);
#pragma unroll
        for (int j = 0; j < 4; ++j) {
            const int nf = nb + j;
            if (nf < 7) {
                const int rn = nf * 16 + l15;
                const char* bp = (const char*)(bb + (size_t)rn * 32);
                const bf16x8 bfr = *reinterpret_cast<const bf16x8*>(
                    bp + ((lk * 16) ^ ((rn & 3) << 4)));
                acc[j] = __builtin_amdgcn_mfma_f32_16x16x32_bf16(af, bfr, acc[j], 0, 0, 0);
            }
        }
    };

    float* X0 = &xs[0][0][0]; unsigned short* B0 = &bs[0][0][0];
    float* X1 = &xs[1][0][0]; unsigned short* B1 = &bs[1][0][0];
    float* X2 = &xs[2][0][0]; unsigned short* B2 = &bs[2][0][0];

    // ---- GEMM1: 24 stages of 32 (k 0..767), counted-vmcnt pipeline
    issue(0, X0, B0);
    issue(1, X1, B1);
    WAITV2; BAR;                       // stage 0 landed; stage 1 in flight
#pragma unroll 1
    for (int tt = 0; tt < 7; ++tt) {
        const int t = tt * 3;
        issue(t + 2, X2, B2); computeStage(X0, B0); WAITV2; BAR;
        issue(t + 3, X0, B0); computeStage(X1, B1); WAITV2; BAR;
        issue(t + 4, X1, B1); computeStage(X2, B2); WAITV2; BAR;
    }
    issue(23, X2, B2); computeStage(X0, B0); WAITV2; BAR;   // t=21
    computeStage(X1, B1); WAITV0; BAR;                      // t=22
    computeStage(X2, B2);                                   // t=23

    // ---- GEMM1 tail: k 768..783 from global (weff zero-pad kills k>=784)
    {
        float4 t0 = (float4){0.f, 0.f, 0.f, 0.f}, t1 = t0;
        if (lk < 2) {
            const float* xp = x + (size_t)(b0 + wr + l15) * 784 + 768 + lk * 8;
            t0 = *reinterpret_cast<const float4*>(xp);
            t1 = *reinterpret_cast<const float4*>(xp + 4);
        }
        const bf16x8 aft = cvt8(t0, t1);
#pragma unroll
        for (int j = 0; j < 4; ++j) {
            const int nf = nb + j;
            if (nf < 7) {
                const bf16x8 bft = *reinterpret_cast<const bf16x8*>(
                    weff + (size_t)(nf * 16 + l15) * KP1 + 768 + lk * 8);
                acc[j] = __builtin_amdgcn_mfma_f32_16x16x32_bf16(aft, bft, acc[j], 0, 0, 0);
            }
        }
    }
    __syncthreads();   // all xs reads done; h2-alias region reusable

    // ---- h1 = relu(acc + b1) -> LDS; wv_n==1 zeroes k-pads of h1 AND h2
    float bias[4];
#pragma unroll
    for (int j = 0; j < 4; ++j) {
        const int c = (nb + j) * 16 + l15;
        bias[j] = (nb + j < 7 && c < 100) ? b1[c] : 0.f;
    }
#pragma unroll
    for (int j = 0; j < 4; ++j) {
        const int nf = nb + j;
        const int col = nf * 16 + l15;
        if (nf < 7 && col < 100)
#pragma unroll
            for (int q = 0; q < 4; ++q) {
                const float v = fmaxf(acc[j][q] + bias[j], 0.f);
                h1[wr + lk * 4 + q][col] = f2bf(v);
            }
    }
    if (wv_n == 1) {
        for (int f = lane; f < 16 * 14; f += 64) {
            const int r = wr + f / 14, c = 100 + (f % 14) * 2;
            *reinterpret_cast<unsigned int*>(&h1[r][c]) = 0u;
            *reinterpret_cast<unsigned int*>(&h2[r][c]) = 0u;
        }
    }
    __syncthreads();

    // ---- GEMM2: h2 = relu(h1 @ W2 + b2)
    f32x4 acc2[4];
#pragma unroll
    for (int j = 0; j < 4; ++j) acc2[j] = (f32x4){0.f, 0.f, 0.f, 0.f};
#pragma unroll
    for (int ks = 0; ks < 4; ++ks) {
        const int kb = ks * 32 + lk * 8;
        const bf16x8 af = *reinterpret_cast<const bf16x8*>(&h1[wr + l15][kb]);
#pragma unroll
        for (int j = 0; j < 4; ++j) {
            const int nf = nb + j;
            if (nf < 7) {
                const bf16x8 bfr = *reinterpret_cast<const bf16x8*>(
                    w2t + (size_t)(nf * 16 + l15) * K2P + kb);
                acc2[j] = __builtin_amdgcn_mfma_f32_16x16x32_bf16(af, bfr, acc2[j], 0, 0, 0);
            }
        }
    }

#pragma unroll
    for (int j = 0; j < 4; ++j) {
        const int c = (nb + j) * 16 + l15;
        bias[j] = (nb + j < 7 && c < 100) ? b2[c] : 0.f;
    }
#pragma unroll
    for (int j = 0; j < 4; ++j) {
        const int nf = nb + j;
        const int col = nf * 16 + l15;
        if (nf < 7 && col < 100)
#pragma unroll
            for (int q = 0; q < 4; ++q) {
                const float v = fmaxf(acc2[j][q] + bias[j], 0.f);
                h2[wr + lk * 4 + q][col] = f2bf(v);
            }
    }
    __syncthreads();

    // ---- GEMM3: out = h2 @ W3 + b3 (both wv_n compute; wv_n==0 stores)
    f32x4 acc3 = (f32x4){0.f, 0.f, 0.f, 0.f};
#pragma unroll
    for (int ks = 0; ks < 4; ++ks) {
        const int kb = ks * 32 + lk * 8;
        const bf16x8 bfr = *reinterpret_cast<const bf16x8*>(
            w3t + (size_t)l15 * K2P + kb);
        const bf16x8 af = *reinterpret_cast<const bf16x8*>(&h2[wr + l15][kb]);
        acc3 = __builtin_amdgcn_mfma_f32_16x16x32_bf16(af, bfr, acc3, 0, 0, 0);
    }

    if (wv_n == 0 && l15 < 10) {
        const float bb = b3[l15];
#pragma unroll
        for (int q = 0; q < 4; ++q) {
            const int row = b0 + wr + lk * 4 + q;
            out[(size_t)row * 10 + l15] = acc3[q] + bb;
        }
    }
}

extern "C" void kernel_launch(void* const* d_in, const int* in_sizes, int n_in,
                              void* d_out, int out_size, void* d_ws, size_t ws_size,
                              hipStream_t stream) {
    const float* x      = (const float*)d_in[0];
    const float* w_conv = (const float*)d_in[1];
    const float* W1     = (const float*)d_in[2];
    const float* b1     = (const float*)d_in[3];
    const float* W2     = (const float*)d_in[4];
    const float* b2     = (const float*)d_in[5];
    const float* W3     = (const float*)d_in[6];
    const float* b3     = (const float*)d_in[7];
    float* out = (float*)d_out;
    unsigned short* ws = (unsigned short*)d_ws;

    build_weights<<<(WS_USHORTS + 255) / 256, 256, 0, stream>>>(w_conv, W1, W2, W3, ws);
    fused<<<32768 / BM, NT, 0, stream>>>(x, ws, b1, b2, b3, out);
}

// Round 9
// 36.466 us; speedup vs baseline: 1.1180x; 1.1180x over previous
//
#include <hip/hip_runtime.h>

// R9: 12 fat stages (BK=64) + counted-vmcnt pipeline that covers HBM latency.
//   x: 3 LDS buffers, issued 2 stages ahead (~1200cy > 900cy HBM lat).
//   B: 2 LDS buffers, issued 1 stage ahead (L2-resident weff, ~300cy).
//   Stage: issueB(t+1) -> issueX(t+2) -> compute(t) -> vmcnt(4) -> s_barrier.
//   FIFO residual is uniformly 4 (newest x-group) despite 4/4/3/3 B issues.
//   h1/h2 alias the xs region (dead after GEMM1) -> LDS 76.7KB, 2 blocks/CU.
//   build_weights: float4-vectorized W1 gather.

typedef __attribute__((ext_vector_type(8))) short bf16x8;
typedef __attribute__((ext_vector_type(4))) float f32x4;

#define KP1 832     // Weff K padded (784 -> 13*64)
#define NP  112     // hidden N padded (100 -> 7*16)
#define K2P 128     // GEMM2/3 K padded
#define BM  64
#define NT  256

#define W2T_OFF (NP * KP1)              // 93184
#define W3T_OFF (W2T_OFF + NP * K2P)    // 107520
#define WS_USHORTS (W3T_OFF + 16 * K2P) // 109568

#define WAITV4 asm volatile("s_waitcnt vmcnt(4)" ::: "memory")
#define WAITV0 asm volatile("s_waitcnt vmcnt(0)" ::: "memory")
#define BAR    __builtin_amdgcn_s_barrier()
#define SBAR0  __builtin_amdgcn_sched_barrier(0)

__device__ __forceinline__ unsigned short f2bf(float f) {
    unsigned int u = __float_as_uint(f);
    u += 0x7FFFu + ((u >> 16) & 1u);    // RNE
    return (unsigned short)(u >> 16);
}

__device__ __forceinline__ unsigned int pkbf(float a, float b) {
    unsigned int r;
    asm("v_cvt_pk_bf16_f32 %0, %1, %2" : "=v"(r) : "v"(a), "v"(b));
    return r;
}

__device__ __forceinline__ bf16x8 cvt8(float4 a, float4 b) {
    union { unsigned int w[4]; bf16x8 v; } u;
    u.w[0] = pkbf(a.x, a.y);
    u.w[1] = pkbf(a.z, a.w);
    u.w[2] = pkbf(b.x, b.y);
    u.w[3] = pkbf(b.z, b.w);
    return u.v;
}

__device__ __forceinline__ void gload_lds16(const void* g, void* l) {
    __builtin_amdgcn_global_load_lds(
        (const __attribute__((address_space(1))) unsigned int*)g,
        (__attribute__((address_space(3))) unsigned int*)l, 16, 0, 0);
}

// ---------------- Kernel A: weights -> bf16, transposed, padded
//   weff part vectorized: thread = (j4, p), float4 read of W1 row, 4 cols.
__global__ void build_weights(const float* __restrict__ w_conv,
                              const float* __restrict__ W1,
                              const float* __restrict__ W2,
                              const float* __restrict__ W3,
                              unsigned short* __restrict__ ws) {
    const int idx = blockIdx.x * 256 + threadIdx.x;
    const int WEFF_T = 28 * KP1;                 // 28 j-quads x 832 p
    if (idx < WEFF_T) {
        const int j4 = idx / KP1, p = idx % KP1;
        const int j = j4 * 4;
        float a0 = 0.f, a1 = 0.f, a2 = 0.f, a3 = 0.f;
        if (p < 784 && j4 < 25) {
            const int y = p / 28, xx = p % 28;
#pragma unroll
            for (int ky = 0; ky < 3; ++ky) {
                const int py = y - ky;
                if (py < 0 || py >= 26) continue;
#pragma unroll
                for (int kx = 0; kx < 3; ++kx) {
                    const int px = xx - kx;
                    if (px < 0 || px >= 26) continue;
                    const float wc = w_conv[ky * 3 + kx];
                    const float4 w = *reinterpret_cast<const float4*>(
                        W1 + (size_t)(py * 26 + px) * 100 + j);
                    a0 = fmaf(wc, w.x, a0); a1 = fmaf(wc, w.y, a1);
                    a2 = fmaf(wc, w.z, a2); a3 = fmaf(wc, w.w, a3);
                }
            }
        }
        ws[(size_t)(j + 0) * KP1 + p] = f2bf(a0);
        ws[(size_t)(j + 1) * KP1 + p] = f2bf(a1);
        ws[(size_t)(j + 2) * KP1 + p] = f2bf(a2);
        ws[(size_t)(j + 3) * KP1 + p] = f2bf(a3);
    } else if (idx < WEFF_T + NP * K2P) {        // w2t[col][k]
        const int r = idx - WEFF_T;
        const int col = r / K2P, k = r % K2P;
        float v = (col < 100 && k < 100) ? W2[k * 100 + col] : 0.f;
        ws[W2T_OFF + r] = f2bf(v);
    } else if (idx < WEFF_T + NP * K2P + 16 * K2P) {  // w3t[col][k]
        const int r = idx - WEFF_T - NP * K2P;
        const int col = r / K2P, k = r % K2P;
        float v = (col < 10 && k < 100) ? W3[k * 10 + col] : 0.f;
        ws[W3T_OFF + r] = f2bf(v);
    }
}

// ---------------- Kernel B: fused
__global__ __launch_bounds__(NT, 2)
void fused(const float* __restrict__ x,
           const unsigned short* __restrict__ wst,
           const float* __restrict__ b1,
           const float* __restrict__ b2,
           const float* __restrict__ b3,
           float* __restrict__ out) {
    __shared__ __attribute__((aligned(16))) float          xs[3][64][64];   // 49152 B
    __shared__ __attribute__((aligned(16))) unsigned short bs[2][112][64];  // 28672 B
    // h1/h2 alias xs (dead after GEMM1): h1 @ +0, h2 @ +17408 (both 64x136 u16)
    unsigned short (*h1)[136] = reinterpret_cast<unsigned short(*)[136]>(&xs[0][0][0]);
    unsigned short (*h2)[136] = reinterpret_cast<unsigned short(*)[136]>(
        (char*)&xs[0][0][0] + 17408);

    const int tid  = threadIdx.x;
    const int lane = tid & 63;
    const int wv   = tid >> 6;       // wave owns rows wv*16 .. wv*16+15
    const int l15  = lane & 15;
    const int lk   = lane >> 4;      // 0..3
    const int b0   = blockIdx.x * BM;
    const int wr   = wv * 16;

    const unsigned short* weff = wst;
    const unsigned short* w2t  = wst + W2T_OFF;
    const unsigned short* w3t  = wst + W3T_OFF;

    f32x4 acc[7];
#pragma unroll
    for (int n = 0; n < 7; ++n) acc[n] = (f32x4){0.f, 0.f, 0.f, 0.f};

    // ---- staging: 4 x-issues/wave (rows wr..wr+15), 4/4/3/3 B-issues/wave
    auto issueX = [&](int kt, float* xb) {
#pragma unroll
        for (int q = 0; q < 4; ++q) {
            const int rowbase = wr + 4 * q;
            const int r = rowbase + (lane >> 4);
            const int chunk = (lane & 15) ^ (r & 7);       // low-3-bit inverse swz
            const char* g = (const char*)(x + (size_t)(b0 + r) * 784 + kt * 64)
                          + chunk * 16;
            gload_lds16(g, (char*)xb + rowbase * 256);
        }
    };
    auto issueB = [&](int kt, unsigned short* bb) {
#pragma unroll
        for (int k = 0; k < 4; ++k) {
            const int i = wv + 4 * k;
            if (i < 14) {
                const int rowbase = 8 * i;
                const int r = rowbase + (lane >> 3);
                const int chunk = (lane & 7) ^ (r & 7);
                const char* g = (const char*)(weff + (size_t)r * KP1 + kt * 64)
                              + chunk * 16;
                gload_lds16(g, (char*)bb + rowbase * 128);
            }
        }
    };

    auto computeStage = [&](const float* xb, const unsigned short* bb) {
        const int r = wr + l15;
        const int sA = (r & 7) << 4;
        const char* ap = (const char*)xb + r * 256;
#pragma unroll
        for (int ks = 0; ks < 2; ++ks) {
            const int base = ks * 128 + lk * 32;
            const float4 lo = *reinterpret_cast<const float4*>(ap + ((base     ) ^ sA));
            const float4 hi = *reinterpret_cast<const float4*>(ap + ((base + 16) ^ sA));
            const bf16x8 af = cvt8(lo, hi);
#pragma unroll
            for (int n = 0; n < 7; ++n) {
                const int rn = n * 16 + l15;
                const char* bp = (const char*)bb + rn * 128;
                const bf16x8 bfr = *reinterpret_cast<const bf16x8*>(
                    bp + ((ks * 64 + lk * 16) ^ ((rn & 7) << 4)));
                acc[n] = __builtin_amdgcn_mfma_f32_16x16x32_bf16(af, bfr, acc[n], 0, 0, 0);
            }
        }
    };

    float*          X[3] = {&xs[0][0][0], &xs[1][0][0], &xs[2][0][0]};
    unsigned short* Bf[2] = {&bs[0][0][0], &bs[1][0][0]};

    // ---- GEMM1: 12 stages of 64 (k 0..767)
    issueX(0, X[0]); issueB(0, Bf[0]); issueX(1, X[1]);
    WAITV4; BAR;                     // x0,B0 landed; x1 in flight
#pragma unroll
    for (int t = 0; t < 12; ++t) {
        if (t < 11) issueB(t + 1, Bf[(t + 1) & 1]);
        if (t < 10) issueX(t + 2, X[(t + 2) % 3]);
        SBAR0;                       // issues stay before compute
        computeStage(X[t % 3], Bf[t & 1]);
        if (t < 10)      { WAITV4; BAR; }
        else if (t == 10){ WAITV0; BAR; }
    }

    // ---- GEMM1 tail: k 768..783 from global (weff zero-pad kills k>=784)
    {
        float4 t0 = (float4){0.f, 0.f, 0.f, 0.f}, t1 = t0;
        if (lk < 2) {
            const float* xp = x + (size_t)(b0 + wr + l15) * 784 + 768 + lk * 8;
            t0 = *reinterpret_cast<const float4*>(xp);
            t1 = *reinterpret_cast<const float4*>(xp + 4);
        }
        const bf16x8 aft = cvt8(t0, t1);
#pragma unroll
        for (int n = 0; n < 7; ++n) {
            const bf16x8 bft = *reinterpret_cast<const bf16x8*>(
                weff + (size_t)(n * 16 + l15) * KP1 + 768 + lk * 8);
            acc[n] = __builtin_amdgcn_mfma_f32_16x16x32_bf16(aft, bft, acc[n], 0, 0, 0);
        }
    }
    __syncthreads();     // all xs reads done -> h1/h2 alias region now safe

    // ---- h1 = relu(acc + b1) -> LDS (own rows); zero h1/h2 k-pads
    float bias[7];
#pragma unroll
    for (int n = 0; n < 7; ++n) {
        const int c = n * 16 + l15;
        bias[n] = (c < 100) ? b1[c] : 0.f;
    }
#pragma unroll
    for (int n = 0; n < 7; ++n) {
        const int col = n * 16 + l15;
        if (col < 100)
#pragma unroll
            for (int q = 0; q < 4; ++q) {
                const float v = fmaxf(acc[n][q] + bias[n], 0.f);
                h1[wr + lk * 4 + q][col] = f2bf(v);
            }
    }
    for (int f = lane; f < 16 * 14; f += 64) {   // own rows, cols 100..127
        const int r = wr + f / 14, c = 100 + (f % 14) * 2;
        *reinterpret_cast<unsigned int*>(&h1[r][c]) = 0u;
        *reinterpret_cast<unsigned int*>(&h2[r][c]) = 0u;
    }
    SBAR0;

    // ---- GEMM2: h2 = relu(h1 @ W2 + b2), B direct from global (L2)
    f32x4 acc2[7];
#pragma unroll
    for (int n = 0; n < 7; ++n) acc2[n] = (f32x4){0.f, 0.f, 0.f, 0.f};
#pragma unroll
    for (int ks = 0; ks < 4; ++ks) {
        const int kb = ks * 32 + lk * 8;
        const bf16x8 af = *reinterpret_cast<const bf16x8*>(&h1[wr + l15][kb]);
#pragma unroll
        for (int n = 0; n < 7; ++n) {
            const bf16x8 bfr = *reinterpret_cast<const bf16x8*>(
                w2t + (size_t)(n * 16 + l15) * K2P + kb);
            acc2[n] = __builtin_amdgcn_mfma_f32_16x16x32_bf16(af, bfr, acc2[n], 0, 0, 0);
        }
    }

#pragma unroll
    for (int n = 0; n < 7; ++n) {
        const int c = n * 16 + l15;
        bias[n] = (c < 100) ? b2[c] : 0.f;
    }
#pragma unroll
    for (int n = 0; n < 7; ++n) {
        const int col = n * 16 + l15;
        if (col < 100)
#pragma unroll
            for (int q = 0; q < 4; ++q) {
                const float v = fmaxf(acc2[n][q] + bias[n], 0.f);
                h2[wr + lk * 4 + q][col] = f2bf(v);
            }
    }
    SBAR0;

    // ---- GEMM3: out = h2 @ W3 + b3
    f32x4 acc3 = (f32x4){0.f, 0.f, 0.f, 0.f};
#pragma unroll
    for (int ks = 0; ks < 4; ++ks) {
        const int kb = ks * 32 + lk * 8;
        const bf16x8 bfr = *reinterpret_cast<const bf16x8*>(
            w3t + (size_t)l15 * K2P + kb);
        const bf16x8 af = *reinterpret_cast<const bf16x8*>(&h2[wr + l15][kb]);
        acc3 = __builtin_amdgcn_mfma_f32_16x16x32_bf16(af, bfr, acc3, 0, 0, 0);
    }

    if (l15 < 10) {
        const float bb = b3[l15];
#pragma unroll
        for (int q = 0; q < 4; ++q) {
            const int row = b0 + wr + lk * 4 + q;
            out[(size_t)row * 10 + l15] = acc3[q] + bb;
        }
    }
}

extern "C" void kernel_launch(void* const* d_in, const int* in_sizes, int n_in,
                              void* d_out, int out_size, void* d_ws, size_t ws_size,
                              hipStream_t stream) {
    const float* x      = (const float*)d_in[0];
    const float* w_conv = (const float*)d_in[1];
    const float* W1     = (const float*)d_in[2];
    const float* b1     = (const float*)d_in[3];
    const float* W2     = (const float*)d_in[4];
    const float* b2     = (const float*)d_in[5];
    const float* W3     = (const float*)d_in[6];
    const float* b3     = (const float*)d_in[7];
    float* out = (float*)d_out;
    unsigned short* ws = (unsigned short*)d_ws;

    const int total = 28 * KP1 + NP * K2P + 16 * K2P;   // 39680
    build_weights<<<(total + 255) / 256, 256, 0, stream>>>(w_conv, W1, W2, W3, ws);
    fused<<<32768 / BM, NT, 0, stream>>>(x, ws, b1, b2, b3, out);
}